// Round 14
// baseline (330.686 us; speedup 1.0000x reference)
//
#include <hip/hip_runtime.h>

typedef float f32x4 __attribute__((ext_vector_type(4)));
typedef __bf16 bf16x8 __attribute__((ext_vector_type(8)));
typedef unsigned int u32;

#define DEV __device__ __forceinline__
#define WAITVM(n) asm volatile("s_waitcnt vmcnt(" #n ")" ::: "memory")

// async global->LDS, 16B per lane. LDS dest = wave-uniform base + lane*16.
DEV void gload_lds16(const void* g, void* l) {
  __builtin_amdgcn_global_load_lds(
      (const __attribute__((address_space(1))) u32*)g,
      (__attribute__((address_space(3))) u32*)l, 16, 0, 0);
}

// bijective XCD swizzle for nwg % 8 == 0: hw flat id -> logical tile id
DEV int xcd_swz(int flat, int nwg) {
  return (flat & 7) * (nwg >> 3) + (flat >> 3);
}

// ---------------------------------------------------------------- weights cast
__global__ __launch_bounds__(256) void cvt_all(const float* __restrict__ s0,
                                               const float* __restrict__ s1,
                                               const float* __restrict__ s2,
                                               const float* __restrict__ s3,
                                               const float* __restrict__ s4,
                                               __bf16* __restrict__ d0,
                                               __bf16* __restrict__ d1,
                                               __bf16* __restrict__ d2,
                                               __bf16* __restrict__ d3,
                                               __bf16* __restrict__ d4) {
  size_t i = ((size_t)blockIdx.x * 256 + threadIdx.x) * 8;
  const float* s; __bf16* d; size_t off;
  if (i < 3145728)        { s = s0; d = d0; off = 0; }
  else if (i < 4194304)   { s = s1; d = d1; off = 3145728; }
  else if (i < 8388608)   { s = s2; d = d2; off = 4194304; }
  else if (i < 12582912)  { s = s3; d = d3; off = 8388608; }
  else                    { s = s4; d = d4; off = 12582912; }
  const size_t j = i - off;
  float4 a = *(const float4*)(s + j);
  float4 b = *(const float4*)(s + j + 4);
  union { bf16x8 v; __bf16 e[8]; } u;
  u.e[0] = (__bf16)a.x; u.e[1] = (__bf16)a.y; u.e[2] = (__bf16)a.z; u.e[3] = (__bf16)a.w;
  u.e[4] = (__bf16)b.x; u.e[5] = (__bf16)b.y; u.e[6] = (__bf16)b.z; u.e[7] = (__bf16)b.w;
  *(bf16x8*)(d + j) = u.v;
}

// ---------------------------------------------------------------- layernorm
__global__ __launch_bounds__(256) void ln_kernel(const float* __restrict__ x,
                                                 const float* __restrict__ w,
                                                 const float* __restrict__ b,
                                                 __bf16* __restrict__ o) {
  const int row = blockIdx.x, tid = threadIdx.x;
  const float4 v = ((const float4*)(x + (size_t)row * 1024))[tid];
  float s  = v.x + v.y + v.z + v.w;
  float s2 = v.x * v.x + v.y * v.y + v.z * v.z + v.w * v.w;
  for (int off = 32; off; off >>= 1) {
    s  += __shfl_down(s, off);
    s2 += __shfl_down(s2, off);
  }
  __shared__ float rs[4], rs2[4];
  if ((tid & 63) == 0) { rs[tid >> 6] = s; rs2[tid >> 6] = s2; }
  __syncthreads();
  float S = rs[0] + rs[1] + rs[2] + rs[3];
  float S2 = rs2[0] + rs2[1] + rs2[2] + rs2[3];
  float mean = S * (1.0f / 1024.0f);
  float var = S2 * (1.0f / 1024.0f) - mean * mean;
  float inv = rsqrtf(var + 1e-5f);
  const float4 wv = ((const float4*)w)[tid];
  const float4 bv = ((const float4*)b)[tid];
  union { ushort4 u4; __bf16 e[4]; } u;
  u.e[0] = (__bf16)((v.x - mean) * inv * wv.x + bv.x);
  u.e[1] = (__bf16)((v.y - mean) * inv * wv.y + bv.y);
  u.e[2] = (__bf16)((v.z - mean) * inv * wv.z + bv.z);
  u.e[3] = (__bf16)((v.w - mean) * inv * wv.w + bv.w);
  *(ushort4*)(o + (size_t)row * 1024 + tid * 4) = u.u4;
}

// LDS chunk-rotate layout per 16-row group (0 conflicts, R6-verified):
// stage slot s holds global chunk ((s&3)-((s>>3)&3))&3 of row s>>2;
// read at c8 = ((g + (l15>>1))&3)*8 recovers chunk g conflict-free.

// ---------------------------------------------------------------- GEMM (R11-exact)
template <int EPI, int MI>
__global__ __launch_bounds__(256) void gemm_bt(const __bf16* __restrict__ A,
                                               const __bf16* __restrict__ B,
                                               void* __restrict__ Cout,
                                               const float* __restrict__ Res,
                                               int M, int N, int K) {
  constexpr int BM = MI * 32;
  __shared__ __align__(16) __bf16 As[3][BM * 32];
  __shared__ __align__(16) __bf16 Bs[3][128 * 32];
  const int tid = threadIdx.x;
  const int lane = tid & 63;
  const int w = tid >> 6;
  const int wr = w >> 1, wc = w & 1;
  const int l15 = lane & 15, g = lane >> 4;
  const int c8 = ((g + (l15 >> 1)) & 3) * 8;

  const int nbx = gridDim.x;
  const int logical = xcd_swz(blockIdx.y * nbx + blockIdx.x, nbx * gridDim.y);
  const int per = 8 * nbx, grp = logical / per, rem = logical % per;
  const int bm = (grp * 8 + (rem & 7)) * BM;
  const int bn = (rem >> 3) * 128;

  f32x4 acc[MI][4] = {};

  auto stage = [&](int buf, int k0) {
#pragma unroll
    for (int p = 0; p < MI / 2; ++p) {
      const int ch = p * 256 + tid;
      const int row = ch >> 2;
      const int gc = ((ch & 3) - ((ch >> 3) & 3)) & 3;
      gload_lds16(A + (size_t)(bm + row) * K + k0 + gc * 8,
                  &As[buf][(p * 256 + w * 64) * 8]);
    }
#pragma unroll
    for (int p = 0; p < 2; ++p) {
      const int ch = p * 256 + tid;
      const int row = ch >> 2;
      const int gc = ((ch & 3) - ((ch >> 3) & 3)) & 3;
      gload_lds16(B + (size_t)(bn + row) * K + k0 + gc * 8,
                  &Bs[buf][(p * 256 + w * 64) * 8]);
    }
  };

  const int NT = K >> 5;
  stage(0, 0);
  stage(1, 32);

  int cur = 0;
  for (int t = 0; t < NT; ++t) {
    if (t + 1 < NT) {
      if constexpr (MI == 4) { WAITVM(4); } else { WAITVM(3); }
    } else {
      WAITVM(0);
    }
    __builtin_amdgcn_s_barrier();
    if (t + 2 < NT) {
      int sb = cur + 2; if (sb >= 3) sb -= 3;
      stage(sb, (t + 2) * 32);
    }
    bf16x8 af[MI], bfr[4];
#pragma unroll
    for (int i = 0; i < MI; ++i)
      af[i] = *(const bf16x8*)(&As[cur][(wr * (MI * 16) + i * 16 + l15) * 32 + c8]);
#pragma unroll
    for (int j = 0; j < 4; ++j)
      bfr[j] = *(const bf16x8*)(&Bs[cur][(wc * 64 + j * 16 + l15) * 32 + c8]);
#pragma unroll
    for (int i = 0; i < MI; ++i)
#pragma unroll
      for (int j = 0; j < 4; ++j)
        acc[i][j] = __builtin_amdgcn_mfma_f32_16x16x32_bf16(af[i], bfr[j], acc[i][j], 0, 0, 0);
    cur = (cur == 2) ? 0 : cur + 1;
  }

  const int r0 = bm + wr * (MI * 16) + g * 4;
  const int c0 = bn + wc * 64 + l15;
#pragma unroll
  for (int i = 0; i < MI; ++i)
#pragma unroll
    for (int j = 0; j < 4; ++j)
#pragma unroll
      for (int r = 0; r < 4; ++r) {
        const size_t idx = (size_t)(r0 + i * 16 + r) * N + (c0 + j * 16);
        const float v = acc[i][j][r];
        if (EPI == 0) ((__bf16*)Cout)[idx] = (__bf16)v;
        else          ((float*)Cout)[idx] = v + Res[idx];
      }
}

// ---------------------------------------------------------------- fused MLP gate+up
// 8-phase-style: 256x128 tile, BK=32, 512 thr (8 waves 4Mx2N), 3 LDS buffers,
// per K-tile 2 phases {stage-unit issue -> ds_read -> barrier -> setprio ->
// 16 MFMA -> setprio -> barrier}; counted vmcnt(4) at tile boundary only.
__global__ __launch_bounds__(512) void gemm_mlp8(const __bf16* __restrict__ A,
                                                 const __bf16* __restrict__ BG,
                                                 const __bf16* __restrict__ BU,
                                                 __bf16* __restrict__ H,
                                                 int M, int N, int K) {
  __shared__ __align__(16) __bf16 As[3][256 * 32];   // 48 KB
  __shared__ __align__(16) __bf16 Bg[3][128 * 32];   // 24 KB
  __shared__ __align__(16) __bf16 Bu[3][128 * 32];   // 24 KB
  const int tid = threadIdx.x;
  const int lane = tid & 63;
  const int w = tid >> 6;             // 0..7
  const int wr = w >> 1, wc = w & 1;  // 4M x 2N
  const int l15 = lane & 15, g = lane >> 4;
  const int c8 = ((g + (l15 >> 1)) & 3) * 8;

  const int nbx = gridDim.x;          // 32
  const int logical = xcd_swz(blockIdx.y * nbx + blockIdx.x, nbx * gridDim.y);
  const int per = 8 * nbx, grp = logical / per, rem = logical % per;
  const int bm = (grp * 8 + (rem & 7)) * 256;
  const int bn = (rem >> 3) * 128;

  f32x4 accg[4][4] = {};
  f32x4 accu[4][4] = {};

  // stage unit a: A tile 256x32 (2 loads/thread)
  auto stage_a = [&](int buf, int k0) {
#pragma unroll
    for (int p = 0; p < 2; ++p) {
      const int ch = p * 512 + tid;
      const int row = ch >> 2;
      const int gc = ((ch & 3) - ((ch >> 3) & 3)) & 3;
      gload_lds16(A + (size_t)(bm + row) * K + k0 + gc * 8,
                  &As[buf][(p * 512 + w * 64) * 8]);
    }
  };
  // stage unit b: Bg + Bu tiles 128x32 each (2 loads/thread)
  auto stage_b = [&](int buf, int k0) {
    const int ch = tid;
    const int row = ch >> 2;
    const int gc = ((ch & 3) - ((ch >> 3) & 3)) & 3;
    const size_t ro = (size_t)(bn + row) * K + k0 + gc * 8;
    gload_lds16(BG + ro, &Bg[buf][(w * 64) * 8]);
    gload_lds16(BU + ro, &Bu[buf][(w * 64) * 8]);
  };

  const int NT = K >> 5;  // 32
  stage_a(0, 0);  stage_b(0, 0);
  stage_a(1, 32); stage_b(1, 32);

  for (int t = 0; t < NT; ++t) {
    int cur = t % 3;
    int sb = cur + 2; if (sb >= 3) sb -= 3;
    const bool pre = (t + 2 < NT);

    // tile boundary: retire tile t's 4 loads, keep t+1's 4 in flight
    if (t + 1 < NT) { WAITVM(4); } else { WAITVM(0); }
    __builtin_amdgcn_s_barrier();

    // ---- phase 0: gate matrix ----
    if (pre) stage_a(sb, (t + 2) * 32);
    bf16x8 af[4], bgf[4];
#pragma unroll
    for (int i = 0; i < 4; ++i)
      af[i] = *(const bf16x8*)(&As[cur][(wr * 64 + i * 16 + l15) * 32 + c8]);
#pragma unroll
    for (int j = 0; j < 4; ++j)
      bgf[j] = *(const bf16x8*)(&Bg[cur][(wc * 64 + j * 16 + l15) * 32 + c8]);
    __builtin_amdgcn_s_barrier();
    __builtin_amdgcn_s_setprio(1);
#pragma unroll
    for (int i = 0; i < 4; ++i)
#pragma unroll
      for (int j = 0; j < 4; ++j)
        accg[i][j] = __builtin_amdgcn_mfma_f32_16x16x32_bf16(af[i], bgf[j], accg[i][j], 0, 0, 0);
    __builtin_amdgcn_s_setprio(0);
    __builtin_amdgcn_s_barrier();

    // ---- phase 1: up matrix ----
    if (pre) stage_b(sb, (t + 2) * 32);
    bf16x8 buf_[4];
#pragma unroll
    for (int j = 0; j < 4; ++j)
      buf_[j] = *(const bf16x8*)(&Bu[cur][(wc * 64 + j * 16 + l15) * 32 + c8]);
    __builtin_amdgcn_s_barrier();
    __builtin_amdgcn_s_setprio(1);
#pragma unroll
    for (int i = 0; i < 4; ++i)
#pragma unroll
      for (int j = 0; j < 4; ++j)
        accu[i][j] = __builtin_amdgcn_mfma_f32_16x16x32_bf16(af[i], buf_[j], accu[i][j], 0, 0, 0);
    __builtin_amdgcn_s_setprio(0);
    // closing barrier is the next tile's boundary barrier
  }

  const int r0 = bm + wr * 64 + g * 4;
  const int c0 = bn + wc * 64 + l15;
#pragma unroll
  for (int i = 0; i < 4; ++i)
#pragma unroll
    for (int j = 0; j < 4; ++j)
#pragma unroll
      for (int r = 0; r < 4; ++r) {
        const float gt = accg[i][j][r];
        const float ut = accu[i][j][r];
        const float h = gt / (1.0f + __expf(-gt)) * ut;
        H[(size_t)(r0 + i * 16 + r) * N + (c0 + j * 16)] = (__bf16)h;
      }
}

// ---------------------------------------------------------------- V transpose
__global__ __launch_bounds__(256) void transpose_v(const __bf16* __restrict__ qkv,
                                                   __bf16* __restrict__ vT) {
  const int st = blockIdx.x, bh = blockIdx.y;
  const int b = bh >> 4, h = bh & 15;
  __shared__ __bf16 tile[64][80];
  const int tid = threadIdx.x;
#pragma unroll
  for (int it = 0; it < 2; ++it) {
    const int idx = it * 256 + tid;
    const int r = idx >> 3, c0 = (idx & 7) * 8;
    bf16x8 v = *(const bf16x8*)(qkv + (size_t)(b * 2048 + st * 64 + r) * 3072 + 2048 + h * 64 + c0);
    *(bf16x8*)&tile[r][c0] = v;
  }
  __syncthreads();
#pragma unroll
  for (int it = 0; it < 2; ++it) {
    const int idx = it * 256 + tid;
    const int d = idx >> 3, s0 = (idx & 7) * 8;
    union { bf16x8 v; __bf16 e[8]; } u;
#pragma unroll
    for (int j = 0; j < 8; ++j) u.e[j] = tile[s0 + j][d];
    *(bf16x8*)(vT + (size_t)(bh * 64 + d) * 2048 + st * 64 + s0) = u.v;
  }
}

// ---------------------------------------------------------------- flash attention (split-kv, R11-exact)
__global__ __launch_bounds__(256) void attn_kernel(const __bf16* __restrict__ qkv,
                                                   const __bf16* __restrict__ vT,
                                                   __bf16* __restrict__ Opart,
                                                   float* __restrict__ Lpart) {
  const int logical = xcd_swz(blockIdx.y * 32 + blockIdx.x, 2048);
  const int qt = logical & 31;
  const int rest = logical >> 5;
  const int bh = rest >> 1, half = rest & 1;
  const int b = bh >> 4, h = bh & 15;
  const int tid = threadIdx.x, lane = tid & 63, w = tid >> 6;
  const int l15 = lane & 15, g = lane >> 4;
  const float CSC = 0.125f * 1.44269504f;

  __shared__ __align__(16) __bf16 Ks[64 * 64];
  __shared__ __align__(16) __bf16 Vs[64 * 64];
  __shared__ __align__(16) __bf16 Ps[4][16 * 80];

  const int qrow = qt * 64 + w * 16 + l15;
  const size_t qbase = (size_t)(b * 2048 + qrow) * 3072 + h * 64;
  bf16x8 qf0, qf1;
  {
    union { bf16x8 v; __bf16 e[8]; } a, bq, oa, ob;
    a.v = *(const bf16x8*)(qkv + qbase + g * 8);
    bq.v = *(const bf16x8*)(qkv + qbase + 32 + g * 8);
#pragma unroll
    for (int j = 0; j < 8; ++j) {
      oa.e[j] = (__bf16)((float)a.e[j] * CSC);
      ob.e[j] = (__bf16)((float)bq.e[j] * CSC);
    }
    qf0 = oa.v; qf1 = ob.v;
  }

  f32x4 o_acc[4] = {};
  float l_r[4] = {0.f, 0.f, 0.f, 0.f};

  const size_t kgbase = (size_t)(b * 2048) * 3072 + 1024 + h * 64;
  const size_t vgbase = (size_t)bh * 64 * 2048;

  for (int tt = 0; tt < 16; ++tt) {
    const int kv0 = half * 1024 + tt * 64;
#pragma unroll
    for (int p = 0; p < 2; ++p) {
      const int ch = p * 256 + w * 64 + lane;
      const int row = ch >> 3, c = ch & 7;
      const int gc = c ^ (row & 7);
      gload_lds16(qkv + kgbase + (size_t)(kv0 + row) * 3072 + gc * 8, Ks + (p * 256 + w * 64) * 8);
      gload_lds16(vT + vgbase + (size_t)row * 2048 + kv0 + gc * 8, Vs + (p * 256 + w * 64) * 8);
    }
    WAITVM(0);
    __syncthreads();

    f32x4 sf[4];
    __builtin_amdgcn_s_setprio(1);
#pragma unroll
    for (int ni = 0; ni < 4; ++ni) {
      const int krow = ni * 16 + l15;
      const __bf16* kb = Ks + krow * 64;
      const bf16x8 kf0 = *(const bf16x8*)(kb + ((g ^ (krow & 7)) * 8));
      const bf16x8 kf1 = *(const bf16x8*)(kb + (((4 + g) ^ (krow & 7)) * 8));
      f32x4 z = {0.f, 0.f, 0.f, 0.f};
      z = __builtin_amdgcn_mfma_f32_16x16x32_bf16(qf0, kf0, z, 0, 0, 0);
      z = __builtin_amdgcn_mfma_f32_16x16x32_bf16(qf1, kf1, z, 0, 0, 0);
      sf[ni] = z;
    }
    __builtin_amdgcn_s_setprio(0);

#pragma unroll
    for (int ni = 0; ni < 4; ++ni)
#pragma unroll
      for (int r = 0; r < 4; ++r) {
        const float pv = exp2f(sf[ni][r]);
        sf[ni][r] = pv;
        l_r[r] += pv;
      }

    __bf16* pw = Ps[w];
#pragma unroll
    for (int ni = 0; ni < 4; ++ni)
#pragma unroll
      for (int r = 0; r < 4; ++r) {
        const int row = g * 4 + r;
        const int pc = (ni * 2 + (l15 >> 3)) ^ (row & 7);
        pw[row * 80 + pc * 8 + (l15 & 7)] = (__bf16)sf[ni][r];
      }
    asm volatile("" ::: "memory");
    const bf16x8 pa0 = *(const bf16x8*)(pw + l15 * 80 + ((g ^ (l15 & 7)) * 8));
    const bf16x8 pa1 = *(const bf16x8*)(pw + l15 * 80 + (((4 + g) ^ (l15 & 7)) * 8));

    __builtin_amdgcn_s_setprio(1);
#pragma unroll
    for (int ni = 0; ni < 4; ++ni) {
      const int vrow = ni * 16 + l15;
      const __bf16* vb = Vs + vrow * 64;
      const bf16x8 vf0 = *(const bf16x8*)(vb + ((g ^ (vrow & 7)) * 8));
      const bf16x8 vf1 = *(const bf16x8*)(vb + (((4 + g) ^ (vrow & 7)) * 8));
      o_acc[ni] = __builtin_amdgcn_mfma_f32_16x16x32_bf16(pa0, vf0, o_acc[ni], 0, 0, 0);
      o_acc[ni] = __builtin_amdgcn_mfma_f32_16x16x32_bf16(pa1, vf1, o_acc[ni], 0, 0, 0);
    }
    __builtin_amdgcn_s_setprio(0);
    __syncthreads();
  }

#pragma unroll
  for (int mk = 1; mk < 16; mk <<= 1)
#pragma unroll
    for (int r = 0; r < 4; ++r) l_r[r] += __shfl_xor(l_r[r], mk);

  const size_t obase = (size_t)half * 4194304;
#pragma unroll
  for (int r = 0; r < 4; ++r) {
    const int orow = qt * 64 + w * 16 + g * 4 + r;
    const size_t grow = (size_t)(b * 2048 + orow);
    if (l15 == 0) Lpart[half * 65536 + grow * 16 + h] = l_r[r];
#pragma unroll
    for (int ni = 0; ni < 4; ++ni)
      Opart[obase + grow * 1024 + h * 64 + ni * 16 + l15] = (__bf16)o_acc[ni][r];
  }
}

// ---------------------------------------------------------------- merge halves
__global__ __launch_bounds__(256) void attn_merge(const __bf16* __restrict__ Opart,
                                                  const float* __restrict__ Lpart,
                                                  __bf16* __restrict__ outp) {
  const int row = blockIdx.x, tid = threadIdx.x;
  const int col = tid * 4, h = tid >> 4;
  const float l = Lpart[row * 16 + h] + Lpart[65536 + row * 16 + h];
  const float inv = 1.0f / l;
  union { ushort4 u; __bf16 e[4]; } a, b, o;
  a.u = *(const ushort4*)(Opart + (size_t)row * 1024 + col);
  b.u = *(const ushort4*)(Opart + 4194304 + (size_t)row * 1024 + col);
#pragma unroll
  for (int j = 0; j < 4; ++j)
    o.e[j] = (__bf16)(((float)a.e[j] + (float)b.e[j]) * inv);
  *(ushort4*)(outp + (size_t)row * 1024 + col) = o.u;
}

// ---------------------------------------------------------------- launch
extern "C" void kernel_launch(void* const* d_in, const int* in_sizes, int n_in,
                              void* d_out, int out_size, void* d_ws, size_t ws_size,
                              hipStream_t stream) {
  const float* x     = (const float*)d_in[0];
  const float* Wqkv  = (const float*)d_in[1];
  const float* Wout  = (const float*)d_in[2];
  const float* n1w   = (const float*)d_in[3];
  const float* n1b   = (const float*)d_in[4];
  const float* Wgate = (const float*)d_in[5];
  const float* Wup   = (const float*)d_in[6];
  const float* Wdown = (const float*)d_in[7];
  const float* n2w   = (const float*)d_in[8];
  const float* n2b   = (const float*)d_in[9];
  float* out = (float*)d_out;
  char* ws = (char*)d_ws;
  const size_t MB = 1u << 20;

  __bf16* XN  = (__bf16*)(ws + 0);        //  8 MB
  __bf16* QKV = (__bf16*)(ws + 8 * MB);   // 24 MB
  __bf16* VT  = (__bf16*)(ws + 32 * MB);  //  8 MB
  __bf16* ATT = (__bf16*)(ws + 40 * MB);  //  8 MB
  float*  X2  = (float*)(ws + 48 * MB);   // 16 MB (O-partials live here during attn)
  __bf16* OP  = (__bf16*)(ws + 48 * MB);  // 16 MB: [2][4096][1024] bf16
  __bf16* H   = QKV;                      // 32 MB (qkv/vT dead by then)
  __bf16* WQ  = (__bf16*)(ws + 64 * MB);  //  6 MB (dead after QKV gemm)
  float*  LP  = (float*)(ws + 64 * MB);   // 512 KB (over WQ)
  __bf16* WO  = (__bf16*)(ws + 70 * MB);
  __bf16* WG  = (__bf16*)(ws + 72 * MB);
  __bf16* WU  = (__bf16*)(ws + 80 * MB);
  __bf16* WD  = (__bf16*)(ws + 88 * MB);

  cvt_all<<<16777216 / 2048, 256, 0, stream>>>(Wqkv, Wout, Wgate, Wup, Wdown,
                                               WQ, WO, WG, WU, WD);

  ln_kernel<<<4096, 256, 0, stream>>>(x, n1w, n1b, XN);
  gemm_bt<0, 4><<<dim3(24, 32), 256, 0, stream>>>(XN, WQ, QKV, nullptr, 4096, 3072, 1024);
  transpose_v<<<dim3(32, 32), 256, 0, stream>>>(QKV, VT);
  attn_kernel<<<dim3(32, 64), 256, 0, stream>>>(QKV, VT, OP, LP);
  attn_merge<<<4096, 256, 0, stream>>>(OP, LP, ATT);
  gemm_bt<1, 2><<<dim3(8, 64), 256, 0, stream>>>(ATT, WO, X2, x, 4096, 1024, 1024);
  ln_kernel<<<4096, 256, 0, stream>>>(X2, n2w, n2b, XN);
  gemm_mlp8<<<dim3(32, 16), 512, 0, stream>>>(XN, WG, WU, H, 4096, 4096, 1024);
  gemm_bt<1, 2><<<dim3(8, 64), 256, 0, stream>>>(H, WD, out, X2, 4096, 1024, 4096);

  (void)in_sizes; (void)n_in; (void)out_size; (void)ws_size;
}

// Round 15
// 307.163 us; speedup vs baseline: 1.0766x; 1.0766x over previous
//
#include <hip/hip_runtime.h>

typedef float f32x4 __attribute__((ext_vector_type(4)));
typedef __bf16 bf16x8 __attribute__((ext_vector_type(8)));
typedef unsigned int u32;

#define DEV __device__ __forceinline__
#define WAITVM(n) asm volatile("s_waitcnt vmcnt(" #n ")" ::: "memory")

// async global->LDS, 16B per lane. LDS dest = wave-uniform base + lane*16.
DEV void gload_lds16(const void* g, void* l) {
  __builtin_amdgcn_global_load_lds(
      (const __attribute__((address_space(1))) u32*)g,
      (__attribute__((address_space(3))) u32*)l, 16, 0, 0);
}

// bijective XCD swizzle for nwg % 8 == 0: hw flat id -> logical tile id
DEV int xcd_swz(int flat, int nwg) {
  return (flat & 7) * (nwg >> 3) + (flat >> 3);
}

// ---------------------------------------------------------------- weights cast
__global__ __launch_bounds__(256) void cvt_all(const float* __restrict__ s0,
                                               const float* __restrict__ s1,
                                               const float* __restrict__ s2,
                                               const float* __restrict__ s3,
                                               const float* __restrict__ s4,
                                               __bf16* __restrict__ d0,
                                               __bf16* __restrict__ d1,
                                               __bf16* __restrict__ d2,
                                               __bf16* __restrict__ d3,
                                               __bf16* __restrict__ d4) {
  size_t i = ((size_t)blockIdx.x * 256 + threadIdx.x) * 8;
  const float* s; __bf16* d; size_t off;
  if (i < 3145728)        { s = s0; d = d0; off = 0; }
  else if (i < 4194304)   { s = s1; d = d1; off = 3145728; }
  else if (i < 8388608)   { s = s2; d = d2; off = 4194304; }
  else if (i < 12582912)  { s = s3; d = d3; off = 8388608; }
  else                    { s = s4; d = d4; off = 12582912; }
  const size_t j = i - off;
  float4 a = *(const float4*)(s + j);
  float4 b = *(const float4*)(s + j + 4);
  union { bf16x8 v; __bf16 e[8]; } u;
  u.e[0] = (__bf16)a.x; u.e[1] = (__bf16)a.y; u.e[2] = (__bf16)a.z; u.e[3] = (__bf16)a.w;
  u.e[4] = (__bf16)b.x; u.e[5] = (__bf16)b.y; u.e[6] = (__bf16)b.z; u.e[7] = (__bf16)b.w;
  *(bf16x8*)(d + j) = u.v;
}

// ---------------------------------------------------------------- layernorm
__global__ __launch_bounds__(256) void ln_kernel(const float* __restrict__ x,
                                                 const float* __restrict__ w,
                                                 const float* __restrict__ b,
                                                 __bf16* __restrict__ o) {
  const int row = blockIdx.x, tid = threadIdx.x;
  const float4 v = ((const float4*)(x + (size_t)row * 1024))[tid];
  float s  = v.x + v.y + v.z + v.w;
  float s2 = v.x * v.x + v.y * v.y + v.z * v.z + v.w * v.w;
  for (int off = 32; off; off >>= 1) {
    s  += __shfl_down(s, off);
    s2 += __shfl_down(s2, off);
  }
  __shared__ float rs[4], rs2[4];
  if ((tid & 63) == 0) { rs[tid >> 6] = s; rs2[tid >> 6] = s2; }
  __syncthreads();
  float S = rs[0] + rs[1] + rs[2] + rs[3];
  float S2 = rs2[0] + rs2[1] + rs2[2] + rs2[3];
  float mean = S * (1.0f / 1024.0f);
  float var = S2 * (1.0f / 1024.0f) - mean * mean;
  float inv = rsqrtf(var + 1e-5f);
  const float4 wv = ((const float4*)w)[tid];
  const float4 bv = ((const float4*)b)[tid];
  union { ushort4 u4; __bf16 e[4]; } u;
  u.e[0] = (__bf16)((v.x - mean) * inv * wv.x + bv.x);
  u.e[1] = (__bf16)((v.y - mean) * inv * wv.y + bv.y);
  u.e[2] = (__bf16)((v.z - mean) * inv * wv.z + bv.z);
  u.e[3] = (__bf16)((v.w - mean) * inv * wv.w + bv.w);
  *(ushort4*)(o + (size_t)row * 1024 + tid * 4) = u.u4;
}

// LDS chunk-rotate layout per 16-row group (0 conflicts, R6-verified):
// stage slot s holds global chunk ((s&3)-((s>>3)&3))&3 of row s>>2;
// read at c8 = ((g + (l15>>1))&3)*8 recovers chunk g conflict-free.

// ---------------------------------------------------------------- GEMM
// C[M,N] = A[M,K] * B[N,K]^T ; BM = MI*32 x 128 tile, BK=32, 256 thr (4 waves 2x2)
// 3-buffer counted-vmcnt pipeline, raw s_barrier (1 barrier / K-step).
template <int EPI, int MI>
__global__ __launch_bounds__(256) void gemm_bt(const __bf16* __restrict__ A,
                                               const __bf16* __restrict__ B,
                                               void* __restrict__ Cout,
                                               const float* __restrict__ Res,
                                               int M, int N, int K) {
  constexpr int BM = MI * 32;
  __shared__ __align__(16) __bf16 As[3][BM * 32];
  __shared__ __align__(16) __bf16 Bs[3][128 * 32];
  const int tid = threadIdx.x;
  const int lane = tid & 63;
  const int w = tid >> 6;
  const int wr = w >> 1, wc = w & 1;
  const int l15 = lane & 15, g = lane >> 4;
  const int c8 = ((g + (l15 >> 1)) & 3) * 8;

  const int nbx = gridDim.x;
  const int logical = xcd_swz(blockIdx.y * nbx + blockIdx.x, nbx * gridDim.y);
  const int per = 8 * nbx, grp = logical / per, rem = logical % per;
  const int bm = (grp * 8 + (rem & 7)) * BM;
  const int bn = (rem >> 3) * 128;

  f32x4 acc[MI][4] = {};

  auto stage = [&](int buf, int k0) {
#pragma unroll
    for (int p = 0; p < MI / 2; ++p) {
      const int ch = p * 256 + tid;
      const int row = ch >> 2;
      const int gc = ((ch & 3) - ((ch >> 3) & 3)) & 3;
      gload_lds16(A + (size_t)(bm + row) * K + k0 + gc * 8,
                  &As[buf][(p * 256 + w * 64) * 8]);
    }
#pragma unroll
    for (int p = 0; p < 2; ++p) {
      const int ch = p * 256 + tid;
      const int row = ch >> 2;
      const int gc = ((ch & 3) - ((ch >> 3) & 3)) & 3;
      gload_lds16(B + (size_t)(bn + row) * K + k0 + gc * 8,
                  &Bs[buf][(p * 256 + w * 64) * 8]);
    }
  };

  const int NT = K >> 5;
  stage(0, 0);
  stage(1, 32);

  int cur = 0;
  for (int t = 0; t < NT; ++t) {
    if (t + 1 < NT) {
      if constexpr (MI == 4) { WAITVM(4); } else { WAITVM(3); }
    } else {
      WAITVM(0);
    }
    __builtin_amdgcn_s_barrier();
    if (t + 2 < NT) {
      int sb = cur + 2; if (sb >= 3) sb -= 3;
      stage(sb, (t + 2) * 32);
    }
    bf16x8 af[MI], bfr[4];
#pragma unroll
    for (int i = 0; i < MI; ++i)
      af[i] = *(const bf16x8*)(&As[cur][(wr * (MI * 16) + i * 16 + l15) * 32 + c8]);
#pragma unroll
    for (int j = 0; j < 4; ++j)
      bfr[j] = *(const bf16x8*)(&Bs[cur][(wc * 64 + j * 16 + l15) * 32 + c8]);
#pragma unroll
    for (int i = 0; i < MI; ++i)
#pragma unroll
      for (int j = 0; j < 4; ++j)
        acc[i][j] = __builtin_amdgcn_mfma_f32_16x16x32_bf16(af[i], bfr[j], acc[i][j], 0, 0, 0);
    cur = (cur == 2) ? 0 : cur + 1;
  }

  const int r0 = bm + wr * (MI * 16) + g * 4;
  const int c0 = bn + wc * 64 + l15;
#pragma unroll
  for (int i = 0; i < MI; ++i)
#pragma unroll
    for (int j = 0; j < 4; ++j)
#pragma unroll
      for (int r = 0; r < 4; ++r) {
        const size_t idx = (size_t)(r0 + i * 16 + r) * N + (c0 + j * 16);
        const float v = acc[i][j][r];
        if (EPI == 0) ((__bf16*)Cout)[idx] = (__bf16)v;
        else          ((float*)Cout)[idx] = v + Res[idx];
      }
}

// ---------------------------------------------------------------- fused MLP gate+up
// H = silu(A*BG^T) * (A*BU^T) ; 128x128 tile, BK=32, dual accumulators
__global__ __launch_bounds__(256, 2) void gemm_mlp(const __bf16* __restrict__ A,
                                                   const __bf16* __restrict__ BG,
                                                   const __bf16* __restrict__ BU,
                                                   __bf16* __restrict__ H,
                                                   int M, int N, int K) {
  __shared__ __align__(16) __bf16 As[3][128 * 32];
  __shared__ __align__(16) __bf16 Bg[3][128 * 32];
  __shared__ __align__(16) __bf16 Bu[3][128 * 32];
  const int tid = threadIdx.x;
  const int lane = tid & 63;
  const int w = tid >> 6;
  const int wr = w >> 1, wc = w & 1;
  const int l15 = lane & 15, g = lane >> 4;
  const int c8 = ((g + (l15 >> 1)) & 3) * 8;

  const int nbx = gridDim.x;
  const int logical = xcd_swz(blockIdx.y * nbx + blockIdx.x, nbx * gridDim.y);
  const int per = 8 * nbx, grp = logical / per, rem = logical % per;
  const int bm = (grp * 8 + (rem & 7)) * 128;
  const int bn = (rem >> 3) * 128;

  f32x4 accg[4][4] = {};
  f32x4 accu[4][4] = {};

  auto stage = [&](int buf, int k0) {
#pragma unroll
    for (int p = 0; p < 2; ++p) {
      const int ch = p * 256 + tid;
      const int row = ch >> 2;
      const int gc = ((ch & 3) - ((ch >> 3) & 3)) & 3;
      const int coff = gc * 8;
      const int dst = (p * 256 + w * 64) * 8;
      gload_lds16(A + (size_t)(bm + row) * K + k0 + coff, &As[buf][dst]);
      gload_lds16(BG + (size_t)(bn + row) * K + k0 + coff, &Bg[buf][dst]);
      gload_lds16(BU + (size_t)(bn + row) * K + k0 + coff, &Bu[buf][dst]);
    }
  };

  const int NT = K >> 5;
  stage(0, 0);
  stage(1, 32);

  int cur = 0;
  for (int t = 0; t < NT; ++t) {
    if (t + 1 < NT) { WAITVM(6); } else { WAITVM(0); }
    __builtin_amdgcn_s_barrier();
    if (t + 2 < NT) {
      int sb = cur + 2; if (sb >= 3) sb -= 3;
      stage(sb, (t + 2) * 32);
    }
    bf16x8 af[4], bgf[4], buf_[4];
#pragma unroll
    for (int i = 0; i < 4; ++i)
      af[i] = *(const bf16x8*)(&As[cur][(wr * 64 + i * 16 + l15) * 32 + c8]);
#pragma unroll
    for (int j = 0; j < 4; ++j) {
      bgf[j] = *(const bf16x8*)(&Bg[cur][(wc * 64 + j * 16 + l15) * 32 + c8]);
      buf_[j] = *(const bf16x8*)(&Bu[cur][(wc * 64 + j * 16 + l15) * 32 + c8]);
    }
#pragma unroll
    for (int i = 0; i < 4; ++i)
#pragma unroll
      for (int j = 0; j < 4; ++j) {
        accg[i][j] = __builtin_amdgcn_mfma_f32_16x16x32_bf16(af[i], bgf[j], accg[i][j], 0, 0, 0);
        accu[i][j] = __builtin_amdgcn_mfma_f32_16x16x32_bf16(af[i], buf_[j], accu[i][j], 0, 0, 0);
      }
    cur = (cur == 2) ? 0 : cur + 1;
  }

  const int r0 = bm + wr * 64 + g * 4;
  const int c0 = bn + wc * 64 + l15;
#pragma unroll
  for (int i = 0; i < 4; ++i)
#pragma unroll
    for (int j = 0; j < 4; ++j)
#pragma unroll
      for (int r = 0; r < 4; ++r) {
        const float gt = accg[i][j][r];
        const float ut = accu[i][j][r];
        const float h = gt / (1.0f + __expf(-gt)) * ut;
        H[(size_t)(r0 + i * 16 + r) * N + (c0 + j * 16)] = (__bf16)h;
      }
}

// ---------------------------------------------------------------- V transpose
__global__ __launch_bounds__(256) void transpose_v(const __bf16* __restrict__ qkv,
                                                   __bf16* __restrict__ vT) {
  const int st = blockIdx.x, bh = blockIdx.y;
  const int b = bh >> 4, h = bh & 15;
  __shared__ __bf16 tile[64][80];
  const int tid = threadIdx.x;
#pragma unroll
  for (int it = 0; it < 2; ++it) {
    const int idx = it * 256 + tid;
    const int r = idx >> 3, c0 = (idx & 7) * 8;
    bf16x8 v = *(const bf16x8*)(qkv + (size_t)(b * 2048 + st * 64 + r) * 3072 + 2048 + h * 64 + c0);
    *(bf16x8*)&tile[r][c0] = v;
  }
  __syncthreads();
#pragma unroll
  for (int it = 0; it < 2; ++it) {
    const int idx = it * 256 + tid;
    const int d = idx >> 3, s0 = (idx & 7) * 8;
    union { bf16x8 v; __bf16 e[8]; } u;
#pragma unroll
    for (int j = 0; j < 8; ++j) u.e[j] = tile[s0 + j][d];
    *(bf16x8*)(vT + (size_t)(bh * 64 + d) * 2048 + st * 64 + s0) = u.v;
  }
}

// ---------------------------------------------------------------- flash attention (split-kv)
__global__ __launch_bounds__(256) void attn_kernel(const __bf16* __restrict__ qkv,
                                                   const __bf16* __restrict__ vT,
                                                   __bf16* __restrict__ Opart,
                                                   float* __restrict__ Lpart) {
  const int logical = xcd_swz(blockIdx.y * 32 + blockIdx.x, 2048);
  const int qt = logical & 31;
  const int rest = logical >> 5;
  const int bh = rest >> 1, half = rest & 1;
  const int b = bh >> 4, h = bh & 15;
  const int tid = threadIdx.x, lane = tid & 63, w = tid >> 6;
  const int l15 = lane & 15, g = lane >> 4;
  const float CSC = 0.125f * 1.44269504f;

  __shared__ __align__(16) __bf16 Ks[64 * 64];
  __shared__ __align__(16) __bf16 Vs[64 * 64];
  __shared__ __align__(16) __bf16 Ps[4][16 * 80];

  const int qrow = qt * 64 + w * 16 + l15;
  const size_t qbase = (size_t)(b * 2048 + qrow) * 3072 + h * 64;
  bf16x8 qf0, qf1;
  {
    union { bf16x8 v; __bf16 e[8]; } a, bq, oa, ob;
    a.v = *(const bf16x8*)(qkv + qbase + g * 8);
    bq.v = *(const bf16x8*)(qkv + qbase + 32 + g * 8);
#pragma unroll
    for (int j = 0; j < 8; ++j) {
      oa.e[j] = (__bf16)((float)a.e[j] * CSC);
      ob.e[j] = (__bf16)((float)bq.e[j] * CSC);
    }
    qf0 = oa.v; qf1 = ob.v;
  }

  f32x4 o_acc[4] = {};
  float l_r[4] = {0.f, 0.f, 0.f, 0.f};

  const size_t kgbase = (size_t)(b * 2048) * 3072 + 1024 + h * 64;
  const size_t vgbase = (size_t)bh * 64 * 2048;

  for (int tt = 0; tt < 16; ++tt) {
    const int kv0 = half * 1024 + tt * 64;
#pragma unroll
    for (int p = 0; p < 2; ++p) {
      const int ch = p * 256 + w * 64 + lane;
      const int row = ch >> 3, c = ch & 7;
      const int gc = c ^ (row & 7);
      gload_lds16(qkv + kgbase + (size_t)(kv0 + row) * 3072 + gc * 8, Ks + (p * 256 + w * 64) * 8);
      gload_lds16(vT + vgbase + (size_t)row * 2048 + kv0 + gc * 8, Vs + (p * 256 + w * 64) * 8);
    }
    WAITVM(0);
    __syncthreads();

    f32x4 sf[4];
    __builtin_amdgcn_s_setprio(1);
#pragma unroll
    for (int ni = 0; ni < 4; ++ni) {
      const int krow = ni * 16 + l15;
      const __bf16* kb = Ks + krow * 64;
      const bf16x8 kf0 = *(const bf16x8*)(kb + ((g ^ (krow & 7)) * 8));
      const bf16x8 kf1 = *(const bf16x8*)(kb + (((4 + g) ^ (krow & 7)) * 8));
      f32x4 z = {0.f, 0.f, 0.f, 0.f};
      z = __builtin_amdgcn_mfma_f32_16x16x32_bf16(qf0, kf0, z, 0, 0, 0);
      z = __builtin_amdgcn_mfma_f32_16x16x32_bf16(qf1, kf1, z, 0, 0, 0);
      sf[ni] = z;
    }
    __builtin_amdgcn_s_setprio(0);

#pragma unroll
    for (int ni = 0; ni < 4; ++ni)
#pragma unroll
      for (int r = 0; r < 4; ++r) {
        const float pv = exp2f(sf[ni][r]);
        sf[ni][r] = pv;
        l_r[r] += pv;
      }

    __bf16* pw = Ps[w];
#pragma unroll
    for (int ni = 0; ni < 4; ++ni)
#pragma unroll
      for (int r = 0; r < 4; ++r) {
        const int row = g * 4 + r;
        const int pc = (ni * 2 + (l15 >> 3)) ^ (row & 7);
        pw[row * 80 + pc * 8 + (l15 & 7)] = (__bf16)sf[ni][r];
      }
    asm volatile("" ::: "memory");
    const bf16x8 pa0 = *(const bf16x8*)(pw + l15 * 80 + ((g ^ (l15 & 7)) * 8));
    const bf16x8 pa1 = *(const bf16x8*)(pw + l15 * 80 + (((4 + g) ^ (l15 & 7)) * 8));

    __builtin_amdgcn_s_setprio(1);
#pragma unroll
    for (int ni = 0; ni < 4; ++ni) {
      const int vrow = ni * 16 + l15;
      const __bf16* vb = Vs + vrow * 64;
      const bf16x8 vf0 = *(const bf16x8*)(vb + ((g ^ (vrow & 7)) * 8));
      const bf16x8 vf1 = *(const bf16x8*)(vb + (((4 + g) ^ (vrow & 7)) * 8));
      o_acc[ni] = __builtin_amdgcn_mfma_f32_16x16x32_bf16(pa0, vf0, o_acc[ni], 0, 0, 0);
      o_acc[ni] = __builtin_amdgcn_mfma_f32_16x16x32_bf16(pa1, vf1, o_acc[ni], 0, 0, 0);
    }
    __builtin_amdgcn_s_setprio(0);
    __syncthreads();
  }

#pragma unroll
  for (int mk = 1; mk < 16; mk <<= 1)
#pragma unroll
    for (int r = 0; r < 4; ++r) l_r[r] += __shfl_xor(l_r[r], mk);

  const size_t obase = (size_t)half * 4194304;
#pragma unroll
  for (int r = 0; r < 4; ++r) {
    const int orow = qt * 64 + w * 16 + g * 4 + r;
    const size_t grow = (size_t)(b * 2048 + orow);
    if (l15 == 0) Lpart[half * 65536 + grow * 16 + h] = l_r[r];
#pragma unroll
    for (int ni = 0; ni < 4; ++ni)
      Opart[obase + grow * 1024 + h * 64 + ni * 16 + l15] = (__bf16)o_acc[ni][r];
  }
}

// ---------------------------------------------------------------- merge halves
__global__ __launch_bounds__(256) void attn_merge(const __bf16* __restrict__ Opart,
                                                  const float* __restrict__ Lpart,
                                                  __bf16* __restrict__ outp) {
  const int row = blockIdx.x, tid = threadIdx.x;
  const int col = tid * 4, h = tid >> 4;
  const float l = Lpart[row * 16 + h] + Lpart[65536 + row * 16 + h];
  const float inv = 1.0f / l;
  union { ushort4 u; __bf16 e[4]; } a, b, o;
  a.u = *(const ushort4*)(Opart + (size_t)row * 1024 + col);
  b.u = *(const ushort4*)(Opart + 4194304 + (size_t)row * 1024 + col);
#pragma unroll
  for (int j = 0; j < 4; ++j)
    o.e[j] = (__bf16)(((float)a.e[j] + (float)b.e[j]) * inv);
  *(ushort4*)(outp + (size_t)row * 1024 + col) = o.u;
}

// ---------------------------------------------------------------- launch
extern "C" void kernel_launch(void* const* d_in, const int* in_sizes, int n_in,
                              void* d_out, int out_size, void* d_ws, size_t ws_size,
                              hipStream_t stream) {
  const float* x     = (const float*)d_in[0];
  const float* Wqkv  = (const float*)d_in[1];
  const float* Wout  = (const float*)d_in[2];
  const float* n1w   = (const float*)d_in[3];
  const float* n1b   = (const float*)d_in[4];
  const float* Wgate = (const float*)d_in[5];
  const float* Wup   = (const float*)d_in[6];
  const float* Wdown = (const float*)d_in[7];
  const float* n2w   = (const float*)d_in[8];
  const float* n2b   = (const float*)d_in[9];
  float* out = (float*)d_out;
  char* ws = (char*)d_ws;
  const size_t MB = 1u << 20;

  __bf16* XN  = (__bf16*)(ws + 0);        //  8 MB
  __bf16* QKV = (__bf16*)(ws + 8 * MB);   // 24 MB
  __bf16* VT  = (__bf16*)(ws + 32 * MB);  //  8 MB
  __bf16* ATT = (__bf16*)(ws + 40 * MB);  //  8 MB
  float*  X2  = (float*)(ws + 48 * MB);   // 16 MB (O-partials live here during attn)
  __bf16* OP  = (__bf16*)(ws + 48 * MB);  // 16 MB: [2][4096][1024] bf16
  __bf16* H   = QKV;                      // 32 MB (qkv/vT dead by then)
  __bf16* WQ  = (__bf16*)(ws + 64 * MB);  //  6 MB (dead after QKV gemm)
  float*  LP  = (float*)(ws + 64 * MB);   // 512 KB (over WQ)
  __bf16* WO  = (__bf16*)(ws + 70 * MB);
  __bf16* WG  = (__bf16*)(ws + 72 * MB);
  __bf16* WU  = (__bf16*)(ws + 80 * MB);
  __bf16* WD  = (__bf16*)(ws + 88 * MB);

  cvt_all<<<16777216 / 2048, 256, 0, stream>>>(Wqkv, Wout, Wgate, Wup, Wdown,
                                               WQ, WO, WG, WU, WD);

  ln_kernel<<<4096, 256, 0, stream>>>(x, n1w, n1b, XN);
  gemm_bt<0, 4><<<dim3(24, 32), 256, 0, stream>>>(XN, WQ, QKV, nullptr, 4096, 3072, 1024);
  transpose_v<<<dim3(32, 32), 256, 0, stream>>>(QKV, VT);
  attn_kernel<<<dim3(32, 64), 256, 0, stream>>>(QKV, VT, OP, LP);
  attn_merge<<<4096, 256, 0, stream>>>(OP, LP, ATT);
  gemm_bt<1, 2><<<dim3(8, 64), 256, 0, stream>>>(ATT, WO, X2, x, 4096, 1024, 1024);
  ln_kernel<<<4096, 256, 0, stream>>>(X2, n2w, n2b, XN);
  gemm_mlp<<<dim3(32, 32), 256, 0, stream>>>(XN, WG, WU, H, 4096, 4096, 1024);
  gemm_bt<1, 2><<<dim3(8, 64), 256, 0, stream>>>(H, WD, out, X2, 4096, 1024, 4096);

  (void)in_sizes; (void)n_in; (void)out_size; (void)ws_size;
}